// Round 6
// baseline (362.296 us; speedup 1.0000x reference)
//
#include <hip/hip_runtime.h>
#include <hip/hip_bf16.h>
#include <stdint.h>

#define B_ROWS 8192
#define N_TOT  16384
#define D_DIM  128
// sqrt(1/0.07): fold temperature into the normalized features so
// (s*f_i)·(s*f_j) = sim/TEMP and the epilogue stores acc directly.
#define SCALE_SQRT_INVT 3.7796447300922722f

typedef __bf16 bf16x8 __attribute__((ext_vector_type(8)));
typedef float  f32x4  __attribute__((ext_vector_type(4)));

// ---------------- Kernel 1: normalize rows of concat(q,k) -> bf16 ----------
__global__ void simclr_norm_kernel(const float* __restrict__ q,
                                   const float* __restrict__ k,
                                   unsigned int* __restrict__ fb) {
    const int lane = threadIdx.x & 63;
    const int row  = blockIdx.x * 4 + (threadIdx.x >> 6);
    const float* src = (row < B_ROWS) ? (q + (size_t)row * D_DIM)
                                      : (k + (size_t)(row - B_ROWS) * D_DIM);
    float2 v = ((const float2*)src)[lane];
    float s = v.x * v.x + v.y * v.y;
#pragma unroll
    for (int off = 32; off > 0; off >>= 1) s += __shfl_xor(s, off);
    float rn = SCALE_SQRT_INVT / fmaxf(sqrtf(s), 1e-12f);
    union { __bf16 h[2]; unsigned int u; } pk;
    pk.h[0] = (__bf16)(v.x * rn);
    pk.h[1] = (__bf16)(v.y * rn);
    fb[(size_t)row * 64 + lane] = pk.u;
}

// ---------------- Kernel 2: sim = f f^T with LDS-TRANSPOSED writeout -------
// Block = 64 rows x one 8192-col half. A-stripe in registers. B fragments
// register-double-buffered straight from L2 (fb is 4 MiB, L2-resident) --
// prefetched one full iteration (~5us) ahead, so latency is hidden.
// EPILOGUE TRANSPOSE: acc -> 32KB LDS tile -> each wave stores 2 rows x 512 B
// CONTIGUOUS runs per instruction. Misaligned 512 B run = 9 granules vs 8
// (1.125x write amplification) instead of the old 16-rows-x-64B pattern
// (2x amplification, the ~3.1 TB/s wall of R1-R5).
__global__ __launch_bounds__(256, 2) void simclr_gemm_kernel(
        const unsigned short* __restrict__ fb, float* __restrict__ out) {
    __shared__ char lds[32768];   // 64 rows x 512 B transpose tile

    const int bid = blockIdx.x;   // 0..511
    const int r0  = (bid >> 1) * 64;          // row-slab base
    const int h   = bid & 1;                  // column half
    const int lane = threadIdx.x & 63;
    const int w    = threadIdx.x >> 6;        // wave id 0..3
    const int rl = lane & 15;                 // fragment row index
    const int kg = lane >> 4;                 // k-group

    const char* fbb = (const char*)fb;
    const int cbase = h * 8192;
    const int base_s = (h == 0) ? 1 : 0;      // col shift before special col

    // ---- A fragments: 64 rows x K=128 in registers ----
    bf16x8 afr[4][4];
#pragma unroll
    for (int m = 0; m < 4; ++m)
#pragma unroll
        for (int ks = 0; ks < 4; ++ks)
            afr[m][ks] = *(const bf16x8*)(fbb + (size_t)(r0 + m * 16 + rl) * 256 + ks * 64 + kg * 16);

    // ---- B fragments for tile 0 (wave w covers local cols w*32..w*32+32) --
    bf16x8 bcur[4][2], bnxt[4][2];
#pragma unroll
    for (int ks = 0; ks < 4; ++ks)
#pragma unroll
        for (int n = 0; n < 2; ++n)
            bcur[ks][n] = *(const bf16x8*)(fbb + (size_t)(cbase + w * 32 + n * 16 + rl) * 256 + ks * 64 + kg * 16);

    for (int t = 0; t < 64; ++t) {
        const int c0 = cbase + t * 128;

        // ---- prefetch next tile's B fragments (consumed ~5us later) ----
        if (t < 63) {
#pragma unroll
            for (int ks = 0; ks < 4; ++ks)
#pragma unroll
                for (int n = 0; n < 2; ++n)
                    bnxt[ks][n] = *(const bf16x8*)(fbb + (size_t)(c0 + 128 + w * 32 + n * 16 + rl) * 256 + ks * 64 + kg * 16);
        }
        __builtin_amdgcn_sched_barrier(0);

        // ---- MFMA: 64 rows x 32 cols per wave (swapped operands) ----
        // acc[m][n][reg]: row = m*16 + rl, local col = w*32 + n*16 + kg*4 + reg
        f32x4 acc[4][2];
#pragma unroll
        for (int m = 0; m < 4; ++m)
#pragma unroll
            for (int n = 0; n < 2; ++n) acc[m][n] = (f32x4){0.f, 0.f, 0.f, 0.f};
#pragma unroll
        for (int ks = 0; ks < 4; ++ks)
#pragma unroll
            for (int m = 0; m < 4; ++m)
#pragma unroll
                for (int n = 0; n < 2; ++n)
                    acc[m][n] = __builtin_amdgcn_mfma_f32_16x16x32_bf16(bcur[ks][n], afr[m][ks], acc[m][n], 0, 0, 0);

        // ---- transpose: acc -> LDS [64 rows][512 B], XOR-swizzled ----
#pragma unroll
        for (int m = 0; m < 4; ++m) {
            const int row = m * 16 + rl;
#pragma unroll
            for (int n = 0; n < 2; ++n) {
                const int colb = w * 128 + n * 64 + kg * 16;
                *(f32x4*)(lds + row * 512 + (colb ^ ((row & 7) << 4))) = acc[m][n];
            }
        }
        asm volatile("s_waitcnt lgkmcnt(0)" ::: "memory");
        __builtin_amdgcn_sched_barrier(0);
        __builtin_amdgcn_s_barrier();           // all acc values visible
        __builtin_amdgcn_sched_barrier(0);

        // ---- row-major writeout: 2 rows x 512 B contiguous per instr ----
        // wave w owns rows w*16 .. w*16+16
#pragma unroll
        for (int j = 0; j < 8; ++j) {
            const int row = w * 16 + j * 2 + (lane >> 5);   // 2 rows/instr
            const int i   = r0 + row;
            const int ch  = lane & 31;                      // 16B chunk 0..31
            f32x4 v = *(const f32x4*)(lds + row * 512 + ((ch * 16) ^ ((row & 7) << 4)));
            // special column of row i within this half:
            //   diag (drop) if i's own half == h, else positive (-> col 0)
            const int sc = cbase + (i & (B_ROWS - 1));
            float* orow = out + (size_t)i * (N_TOT - 1);
            const unsigned rel = (unsigned)(sc - c0);
            if (__builtin_expect(rel < 128u, 0)) {
                const bool isdiag = ((i >> 13) == h);
#pragma unroll
                for (int e = 0; e < 4; ++e) {
                    const int c = c0 + ch * 4 + e;
                    const float val = v[e];
                    if (c == sc) { if (!isdiag) orow[0] = val; }
                    else orow[c + base_s - (c > sc)] = val;
                }
            } else {
                const int s = base_s - (c0 > sc ? 1 : 0);   // uniform shift
                __builtin_memcpy(orow + c0 + s + ch * 4, &v, sizeof(v));
            }
        }
        __builtin_amdgcn_sched_barrier(0);
        __builtin_amdgcn_s_barrier();           // reads done before next write
        __builtin_amdgcn_sched_barrier(0);

        // ---- rotate B register buffers (vmcnt wait lands here, late) ----
        if (t < 63) {
#pragma unroll
            for (int ks = 0; ks < 4; ++ks)
#pragma unroll
                for (int n = 0; n < 2; ++n)
                    bcur[ks][n] = bnxt[ks][n];
        }
    }
}

// ---------------- Kernel 3: labels = zeros (int32 0 == fp32 0.0 bits) ------
__global__ void simclr_zero_labels(float* __restrict__ out) {
    out[(size_t)N_TOT * (N_TOT - 1) + blockIdx.x * 256 + threadIdx.x] = 0.0f;
}

extern "C" void kernel_launch(void* const* d_in, const int* in_sizes, int n_in,
                              void* d_out, int out_size, void* d_ws, size_t ws_size,
                              hipStream_t stream) {
    const float* q = (const float*)d_in[0];
    const float* k = (const float*)d_in[1];
    float* out = (float*)d_out;
    unsigned int* fb = (unsigned int*)d_ws;   // 16384*128 bf16 = 4 MiB scratch

    simclr_norm_kernel<<<N_TOT / 4, 256, 0, stream>>>(q, k, fb);
    simclr_zero_labels<<<N_TOT / 256, 256, 0, stream>>>(out);
    simclr_gemm_kernel<<<512, 256, 0, stream>>>((const unsigned short*)d_ws, out);
}